// Round 1
// baseline (7629.933 us; speedup 1.0000x reference)
//
#include <hip/hip_runtime.h>
#include <math.h>

// Problem constants
#define B_    4
#define C_    128
#define H1    130           // conv1 output spatial
#define H2    132           // conv2 / SPEM spatial
#define HW1   (130*130)
#define HW2   (132*132)
#define NBUF  ((size_t)B_*C_*HW2)   // 8,921,088 floats
#define EPS_  1e-5f
#define TILE  16

// ---------------- block reduce ----------------
__device__ __forceinline__ float blockReduceSum(float v) {
  __shared__ float sh[8];
  int lane = threadIdx.x & 63;
  int wid  = threadIdx.x >> 6;
#pragma unroll
  for (int off = 32; off > 0; off >>= 1) v += __shfl_down(v, off, 64);
  __syncthreads();                 // protect sh across repeated calls
  if (lane == 0) sh[wid] = v;
  __syncthreads();
  float r = 0.f;
  if (threadIdx.x == 0) {
    int nw = (blockDim.x + 63) >> 6;
    for (int i = 0; i < nw; ++i) r += sh[i];
  }
  return r;                        // valid on thread 0 only
}

// ---------------- weight transpose: [co][ci][t] -> [ci][t][co] ----------------
__global__ void wtrans(const float* __restrict__ src, float* __restrict__ dst,
                       int Cout, int Cin, int KK) {
  int idx = blockIdx.x * blockDim.x + threadIdx.x;
  int total = Cout * Cin * KK;
  if (idx >= total) return;
  int co  = idx / (Cin * KK);
  int rem = idx % (Cin * KK);
  int ci  = rem / KK;
  int t   = rem % KK;
  dst[((size_t)ci * KK + t) * Cout + co] = src[idx];
}

// ---------------- 3x3 conv with reflect(1)+zero(1) combined padding ----------------
// input Hin x Hin, output (Hin+2) x (Hin+2). P = reflect_pad1(x); conv(P, pad=1).
__global__ __launch_bounds__(256) void conv3_reflect(
    const float* __restrict__ in, const float* __restrict__ wT,
    float* __restrict__ out, int Hin, int Cin, int Cout) {
  const int Hout = Hin + 2;
  const int nt = (Hout + TILE - 1) / TILE;   // 9 for 130/132
  const int ty0 = (blockIdx.x / nt) * TILE;
  const int tx0 = (blockIdx.x % nt) * TILE;
  const int cog = blockIdx.y;
  const int b   = blockIdx.z;
  const int tid = threadIdx.x;
  const int ty = tid >> 4, tx = tid & 15;

  __shared__ float ilds[8][TILE+2][TILE+2];  // 8 * 18 * 18
  float acc[8];
#pragma unroll
  for (int i = 0; i < 8; ++i) acc[i] = 0.f;

  const int nchunk = Cin >> 3;
  for (int cc = 0; cc < nchunk; ++cc) {
    __syncthreads();
    for (int idx = tid; idx < 8*(TILE+2)*(TILE+2); idx += 256) {
      int ci_l = idx / ((TILE+2)*(TILE+2));
      int rem  = idx % ((TILE+2)*(TILE+2));
      int pr = rem / (TILE+2), pc = rem % (TILE+2);
      int p = ty0 - 1 + pr;        // index into P-space (size Hin+2), zero outside
      int q = tx0 - 1 + pc;
      int r = (p < 0 || p > Hin+1) ? -1 : (p == 0 ? 1 : (p == Hin+1 ? Hin-2 : p-1));
      int c = (q < 0 || q > Hin+1) ? -1 : (q == 0 ? 1 : (q == Hin+1 ? Hin-2 : q-1));
      float v = 0.f;
      if (r >= 0 && c >= 0)
        v = in[(((size_t)b*Cin + (cc*8 + ci_l))*Hin + r)*Hin + c];
      ilds[ci_l][pr][pc] = v;
    }
    __syncthreads();
    for (int ci_l = 0; ci_l < 8; ++ci_l) {
      const float* wbase = wT + ((size_t)(cc*8 + ci_l) * 9) * Cout + cog*8;
#pragma unroll
      for (int ky = 0; ky < 3; ++ky) {
#pragma unroll
        for (int kx = 0; kx < 3; ++kx) {
          float v = ilds[ci_l][ty+ky][tx+kx];
          const float* w = wbase + (ky*3 + kx) * Cout;   // wave-uniform -> s_load
#pragma unroll
          for (int co = 0; co < 8; ++co) acc[co] += v * w[co];
        }
      }
    }
  }
  int oh = ty0 + ty, ow = tx0 + tx;
  if (oh < Hout && ow < Hout) {
#pragma unroll
    for (int co = 0; co < 8; ++co)
      out[(((size_t)b*Cout + cog*8 + co)*Hout + oh)*Hout + ow] = acc[co];
  }
}

// ---------------- 7x7 conv, zero pad 3, spatial 132x132 ----------------
__global__ __launch_bounds__(256) void conv7k(
    const float* __restrict__ in, const float* __restrict__ wT,
    float* __restrict__ out, int Cin, int Cout) {
  const int H = H2;
  const int nt = 9;
  const int ty0 = (blockIdx.x / nt) * TILE;
  const int tx0 = (blockIdx.x % nt) * TILE;
  const int cog = blockIdx.y;
  const int b   = blockIdx.z;
  const int tid = threadIdx.x;
  const int ty = tid >> 4, tx = tid & 15;

  __shared__ float ilds[8][TILE+6][TILE+6];  // 8 * 22 * 22
  float acc[8];
#pragma unroll
  for (int i = 0; i < 8; ++i) acc[i] = 0.f;

  const int nchunk = Cin >> 3;
  for (int cc = 0; cc < nchunk; ++cc) {
    __syncthreads();
    for (int idx = tid; idx < 8*(TILE+6)*(TILE+6); idx += 256) {
      int ci_l = idx / ((TILE+6)*(TILE+6));
      int rem  = idx % ((TILE+6)*(TILE+6));
      int pr = rem / (TILE+6), pc = rem % (TILE+6);
      int r = ty0 - 3 + pr;
      int c = tx0 - 3 + pc;
      float v = 0.f;
      if (r >= 0 && r < H && c >= 0 && c < H)
        v = in[(((size_t)b*Cin + (cc*8 + ci_l))*H + r)*H + c];
      ilds[ci_l][pr][pc] = v;
    }
    __syncthreads();
    for (int ci_l = 0; ci_l < 8; ++ci_l) {
      const float* wbase = wT + ((size_t)(cc*8 + ci_l) * 49) * Cout + cog*8;
#pragma unroll
      for (int ky = 0; ky < 7; ++ky) {
#pragma unroll
        for (int kx = 0; kx < 7; ++kx) {
          float v = ilds[ci_l][ty+ky][tx+kx];
          const float* w = wbase + (ky*7 + kx) * Cout;   // wave-uniform -> s_load
#pragma unroll
          for (int co = 0; co < 8; ++co) acc[co] += v * w[co];
        }
      }
    }
  }
  int oh = ty0 + ty, ow = tx0 + tx;
  if (oh < H && ow < H) {
#pragma unroll
    for (int co = 0; co < 8; ++co)
      out[(((size_t)b*Cout + cog*8 + co)*H + oh)*H + ow] = acc[co];
  }
}

// ---------------- per-(b,c) mean/var ----------------
__global__ void stat2(const float* __restrict__ x, int n,
                      float* __restrict__ mean, float* __restrict__ var) {
  size_t base = (size_t)blockIdx.x * n;
  float s = 0.f, s2 = 0.f;
  for (int i = threadIdx.x; i < n; i += blockDim.x) {
    float v = x[base + i];
    s += v; s2 += v * v;
  }
  float ts  = blockReduceSum(s);
  float ts2 = blockReduceSum(s2);
  if (threadIdx.x == 0) {
    float m = ts / n;
    mean[blockIdx.x] = m;
    var[blockIdx.x]  = ts2 / n - m * m;
  }
}

// ---------------- instance norm + relu (in place) ----------------
__global__ void innorm_relu(float* __restrict__ x, const float* __restrict__ mean,
                            const float* __restrict__ var, int n, int total) {
  int idx = blockIdx.x * blockDim.x + threadIdx.x;
  if (idx >= total) return;
  int bc = idx / n;
  float v = (x[idx] - mean[bc]) * rsqrtf(var[bc] + EPS_);
  x[idx] = fmaxf(v, 0.f);
}

// ---------------- instance norm (in place) + analytic DCT-coefficient mean ----------------
// mean_k DCT_ortho(x)_k = (1/N) * sum_n w_n x_n,
// w_n = (sqrt(1/N) - 0.5 sqrt(2/N)) + 0.5 sqrt(2/N) * (-1)^n * cot(pi(2n+1)/(4N))
__global__ void innorm_mdct(float* __restrict__ x, const float* __restrict__ mean,
                            const float* __restrict__ var, float* __restrict__ mdct) {
  const int n = HW2;
  int bc = blockIdx.x;
  size_t base = (size_t)bc * n;
  float m = mean[bc], rs = rsqrtf(var[bc] + EPS_);
  const float Nf = (float)n;
  const float c2 = 0.5f * sqrtf(2.f / Nf);
  const float a  = sqrtf(1.f / Nf) - c2;
  const float piO4N = 3.14159265358979f / (4.f * Nf);
  float wsum = 0.f;
  for (int i = threadIdx.x; i < n; i += blockDim.x) {
    float v = (x[base + i] - m) * rs;
    x[base + i] = v;
    float phi = piO4N * (2.f * i + 1.f);
    float cot = cosf(phi) / sinf(phi);
    float w = a + ((i & 1) ? -c2 : c2) * cot;
    wsum += w * v;
  }
  float t = blockReduceSum(wsum);
  if (threadIdx.x == 0) mdct[bc] = t / Nf;
}

// ---------------- SFOM gate MLP: [4,128] -> relu@W1 -> sigmoid@W2 -> [4,128] ----------------
__global__ void gatek(const float* __restrict__ mdct, const float* __restrict__ w1,
                      const float* __restrict__ w2, float* __restrict__ gate) {
  __shared__ float t1[4][8];
  int tid = threadIdx.x;
  if (tid < 32) {
    int b = tid >> 3, r = tid & 7;
    float s = 0.f;
    for (int c = 0; c < 128; ++c) s += mdct[b*128 + c] * w1[r*128 + c];
    t1[b][r] = fmaxf(s, 0.f);
  }
  __syncthreads();
  if (tid < 512) {
    int b = tid >> 7, c = tid & 127;
    float s = 0.f;
#pragma unroll
    for (int r = 0; r < 8; ++r) s += t1[b][r] * w2[c*8 + r];
    gate[tid] = 1.f / (1.f + expf(-s));
  }
}

// ---------------- SFOM apply: out = sigmoid(x*(1+g)*0.5) * x ----------------
__global__ void sfom_apply(const float* __restrict__ x, const float* __restrict__ gate,
                           float* __restrict__ outb, size_t total) {
  size_t idx = (size_t)blockIdx.x * blockDim.x + threadIdx.x;
  if (idx >= total) return;
  int bc = (int)(idx / HW2);
  float v = x[idx];
  float g = gate[bc];
  float s = 1.f / (1.f + expf(-(v * (1.f + g) * 0.5f)));
  outb[idx] = s * v;
}

// ---------------- batch norm stats (per channel over B,H,W) ----------------
__global__ void bnstat(const float* __restrict__ x, int Cc,
                       float* __restrict__ mean, float* __restrict__ var) {
  int c = blockIdx.x;
  float s = 0.f, s2 = 0.f;
  for (int b = 0; b < 4; ++b) {
    const float* p = x + ((size_t)b * Cc + c) * HW2;
    for (int i = threadIdx.x; i < HW2; i += blockDim.x) {
      float v = p[i]; s += v; s2 += v * v;
    }
  }
  float ts  = blockReduceSum(s);
  float ts2 = blockReduceSum(s2);
  if (threadIdx.x == 0) {
    float m = ts / (4.f * HW2);
    mean[c] = m;
    var[c]  = ts2 / (4.f * HW2) - m * m;
  }
}

// ---------------- batch norm apply + relu (in place) ----------------
__global__ void bnapply(float* __restrict__ x, const float* __restrict__ mean,
                        const float* __restrict__ var, const float* __restrict__ g,
                        const float* __restrict__ bb, int Cc, size_t total) {
  size_t idx = (size_t)blockIdx.x * blockDim.x + threadIdx.x;
  if (idx >= total) return;
  int c = (int)((idx / HW2) % Cc);
  float y = (x[idx] - mean[c]) * rsqrtf(var[c] + EPS_) * g[c] + bb[c];
  x[idx] = fmaxf(y, 0.f);
}

// ---------------- sa = sigmoid(1x1 conv 32->1 + bias) ----------------
__global__ void sak(const float* __restrict__ h, const float* __restrict__ cw,
                    const float* __restrict__ cb, float* __restrict__ sa) {
  int idx = blockIdx.x * blockDim.x + threadIdx.x;
  if (idx >= 4 * HW2) return;
  int b = idx / HW2, p = idx % HW2;
  float s = cb[0];
#pragma unroll
  for (int c = 0; c < 32; ++c) s += h[((size_t)b*32 + c) * HW2 + p] * cw[c];
  sa[idx] = 1.f / (1.f + expf(-s));
}

// ---------------- final: out = sa * sfom_out ----------------
__global__ void finalk(const float* __restrict__ sa, const float* __restrict__ o,
                       float* __restrict__ out, size_t total) {
  size_t idx = (size_t)blockIdx.x * blockDim.x + threadIdx.x;
  if (idx >= total) return;
  int b = (int)(idx / ((size_t)C_ * HW2));
  int p = (int)(idx % HW2);
  out[idx] = sa[b * HW2 + p] * o[idx];
}

extern "C" void kernel_launch(void* const* d_in, const int* in_sizes, int n_in,
                              void* d_out, int out_size, void* d_ws, size_t ws_size,
                              hipStream_t stream) {
  const float* x     = (const float*)d_in[0];
  const float* c1w   = (const float*)d_in[1];
  const float* c2w   = (const float*)d_in[3];
  const float* sa_w1 = (const float*)d_in[5];
  const float* sa_w2 = (const float*)d_in[6];
  const float* dw[6] = {(const float*)d_in[7],  (const float*)d_in[10], (const float*)d_in[13],
                        (const float*)d_in[16], (const float*)d_in[19], (const float*)d_in[22]};
  const float* bg[6] = {(const float*)d_in[8],  (const float*)d_in[11], (const float*)d_in[14],
                        (const float*)d_in[17], (const float*)d_in[20], (const float*)d_in[23]};
  const float* bb[6] = {(const float*)d_in[9],  (const float*)d_in[12], (const float*)d_in[15],
                        (const float*)d_in[18], (const float*)d_in[21], (const float*)d_in[24]};
  const float* cw    = (const float*)d_in[25];
  const float* cb    = (const float*)d_in[26];
  float* out = (float*)d_out;

  float* ws = (float*)d_ws;
  size_t o = 0;
  float* buf0 = ws + o; o += NBUF;
  float* buf1 = ws + o; o += NBUF;
  float* buf2 = ws + o; o += NBUF;
  float* wt_c1 = ws + o; o += 128*128*9;
  float* wt_c2 = ws + o; o += 128*128*9;
  const int spem_ci[6] = {128, 32, 64, 128, 128, 64};
  const int spem_co[6] = {32, 64, 128, 128, 64, 32};
  float* wt_d[6];
  for (int i = 0; i < 6; ++i) { wt_d[i] = ws + o; o += (size_t)spem_co[i]*spem_ci[i]*49; }
  float* inm  = ws + o; o += 512;
  float* inv  = ws + o; o += 512;
  float* mdct = ws + o; o += 512;
  float* gate = ws + o; o += 512;
  float* bnm  = ws + o; o += 128;
  float* bnv  = ws + o; o += 128;
  float* sa   = ws + o; o += (size_t)B_ * HW2;

  // weight transposes (ws is re-poisoned each call; redo every launch)
  {
    int tot = 128*128*9;
    hipLaunchKernelGGL(wtrans, dim3((tot+255)/256), dim3(256), 0, stream, c1w, wt_c1, 128, 128, 9);
    hipLaunchKernelGGL(wtrans, dim3((tot+255)/256), dim3(256), 0, stream, c2w, wt_c2, 128, 128, 9);
    for (int i = 0; i < 6; ++i) {
      int t2 = spem_co[i]*spem_ci[i]*49;
      hipLaunchKernelGGL(wtrans, dim3((t2+255)/256), dim3(256), 0, stream, dw[i], wt_d[i],
                         spem_co[i], spem_ci[i], 49);
    }
  }

  // conv1 (+IN+relu). conv bias cancels under InstanceNorm -> dropped.
  hipLaunchKernelGGL(conv3_reflect, dim3(81, 16, 4), dim3(256), 0, stream, x, wt_c1, buf0, 128, 128, 128);
  hipLaunchKernelGGL(stat2, dim3(512), dim3(256), 0, stream, buf0, HW1, inm, inv);
  { int tot = 512 * HW1;
    hipLaunchKernelGGL(innorm_relu, dim3((tot+255)/256), dim3(256), 0, stream, buf0, inm, inv, HW1, tot); }

  // conv2 (+IN) + fused analytic DCT-mean
  hipLaunchKernelGGL(conv3_reflect, dim3(81, 16, 4), dim3(256), 0, stream, buf0, wt_c2, buf1, 130, 128, 128);
  hipLaunchKernelGGL(stat2, dim3(512), dim3(256), 0, stream, buf1, HW2, inm, inv);
  hipLaunchKernelGGL(innorm_mdct, dim3(512), dim3(256), 0, stream, buf1, inm, inv, mdct);

  // SFOM gate + apply  (idct(gate*dct(x)) == gate*x algebraically)
  hipLaunchKernelGGL(gatek, dim3(1), dim3(512), 0, stream, mdct, sa_w1, sa_w2, gate);
  hipLaunchKernelGGL(sfom_apply, dim3((int)((NBUF+255)/256)), dim3(256), 0, stream, buf1, gate, buf2, NBUF);

  // SPEM pyramid: 128->32->64->128->128->64->32, 7x7 pad3, BN+relu
  float* pin[6]  = {buf2, buf1, buf0, buf1, buf0, buf1};
  float* pout[6] = {buf1, buf0, buf1, buf0, buf1, buf0};
  for (int i = 0; i < 6; ++i) {
    hipLaunchKernelGGL(conv7k, dim3(81, spem_co[i]/8, 4), dim3(256), 0, stream,
                       pin[i], wt_d[i], pout[i], spem_ci[i], spem_co[i]);
    hipLaunchKernelGGL(bnstat, dim3(spem_co[i]), dim3(256), 0, stream, pout[i], spem_co[i], bnm, bnv);
    size_t tot = (size_t)4 * spem_co[i] * HW2;
    hipLaunchKernelGGL(bnapply, dim3((int)((tot+255)/256)), dim3(256), 0, stream,
                       pout[i], bnm, bnv, bg[i], bb[i], spem_co[i], tot);
  }

  // spatial attention + final product
  { int tot = 4 * HW2;
    hipLaunchKernelGGL(sak, dim3((tot+255)/256), dim3(256), 0, stream, buf0, cw, cb, sa); }
  hipLaunchKernelGGL(finalk, dim3((int)((NBUF+255)/256)), dim3(256), 0, stream, sa, buf2, out, NBUF);
}

// Round 2
// 1493.929 us; speedup vs baseline: 5.1073x; 5.1073x over previous
//
#include <hip/hip_runtime.h>
#include <math.h>

#define B_    4
#define C_    128
#define HW1   (130*130)
#define HW2   (132*132)
#define NBUF  ((size_t)B_*C_*HW2)
#define EPS_  1e-5f
#define PI_   3.14159265358979f

typedef _Float16 half8 __attribute__((ext_vector_type(8)));
typedef _Float16 half4_ __attribute__((ext_vector_type(4)));
typedef float    float4_ __attribute__((ext_vector_type(4)));

// ============ weight prep: fp32 OIHW -> f16 [tap][co][ci] ============
__global__ void wprep(const float* __restrict__ src, _Float16* __restrict__ dst,
                      int Cout, int Cin, int K) {
  int idx = blockIdx.x * blockDim.x + threadIdx.x;
  int tot = Cout * Cin * K * K;
  if (idx >= tot) return;
  int co  = idx / (Cin * K * K);
  int rem = idx % (Cin * K * K);
  int ci  = rem / (K * K);
  int tap = rem % (K * K);
  dst[((size_t)tap * Cout + co) * Cin + ci] = (_Float16)src[idx];
}

// ============ NCHW f32 -> NHWC f16 (LDS transpose) ============
__global__ void to_nhwc(const float* __restrict__ in, _Float16* __restrict__ out,
                        int C, int HW) {
  __shared__ float t[32][65];
  int b = blockIdx.z, c0 = blockIdx.y * 32, p0 = blockIdx.x * 64;
  int tid = threadIdx.x;
  for (int i = 0; i < 8; ++i) {
    int e = i * 256 + tid; int cl = e >> 6, pl = e & 63;
    int p = p0 + pl;
    float v = 0.f;
    if (p < HW) v = in[((size_t)b * C + c0 + cl) * HW + p];
    t[cl][pl] = v;
  }
  __syncthreads();
  for (int i = 0; i < 8; ++i) {
    int e = i * 256 + tid; int pl = e >> 5, cl = e & 31;
    int p = p0 + pl;
    if (p < HW) out[((size_t)b * HW + p) * C + c0 + cl] = (_Float16)t[cl][pl];
  }
}

// ============ MFMA implicit-GEMM conv ============
// act: NHWC f16 [b][y][x][ci], wt: [tap][co][ci] f16, out: NHWC f16.
// Block: 256 thr = 4 waves. Block tile: BCO co x (8 rows x 16 x).
// Wave: WCO=BCO/2 co (MR frags) x 4 rows (NR=4 N-frags of 1row x 16x).
// A-frag: lane&15 = co, (lane>>4)*8+j = ci  (global 16B loads, L2-hot)
// B-frag: lane&15 = x-pos, (lane>>4)*8+j = ci (LDS b128, layout below)
// C/D:    col(lane&15) = x-pos, row((lane>>4)*4+reg) = co   [verified mapping]
template<int CIN, int COUT, int K, int HIN, int HOUT, bool REFLECT>
__global__ __launch_bounds__(256) void conv_mfma(
    const _Float16* __restrict__ act, const _Float16* __restrict__ wt,
    _Float16* __restrict__ out) {
  constexpr int BCO = (COUT >= 64) ? 64 : COUT;
  constexpr int WCO = BCO / 2;
  constexpr int MR  = WCO / 16;
  constexpr int PADc = (K - 1) / 2;
  constexpr int XW = 16 + K - 1;       // staged x width
  constexpr int IR = 8 + K - 1;        // staged rows
  constexpr int CH_TOT = IR * 4 * XW;  // 16B chunks
  constexpr int XTILES = (HOUT + 15) / 16;

  __shared__ half8 smem[CH_TOT];       // chunk idx = (row*4 + q)*XW + x

  const int xt = blockIdx.x % XTILES, yt = blockIdx.x / XTILES;
  const int x0 = xt * 16, y0 = yt * 8;
  const int cob = blockIdx.y * BCO;
  const int b = blockIdx.z;
  const int tid = threadIdx.x;
  const int lane = tid & 63, w = tid >> 6;
  const int wc = w & 1, wr = w >> 1;
  const int n = lane & 15, q = lane >> 4;

  float4_ acc[MR][4];
#pragma unroll
  for (int mi = 0; mi < MR; ++mi)
#pragma unroll
    for (int ni = 0; ni < 4; ++ni)
#pragma unroll
      for (int j = 0; j < 4; ++j) acc[mi][ni][j] = 0.f;

  const _Float16* actb = act + (size_t)b * HIN * HIN * CIN;

  for (int cc = 0; cc < CIN / 32; ++cc) {
    __syncthreads();
    // ---- stage input patch (zero-filled borders; reflect+zero for conv1/2) ----
    for (int e = tid; e < CH_TOT; e += 256) {
      int row = e / (4 * XW);
      int rem = e % (4 * XW);
      int qq = rem / XW, lx = rem % XW;
      int ty = y0 + row - PADc;
      int tx = x0 + lx - PADc;
      bool ok; int iy, ix;
      if (REFLECT) {   // P-space coords; P = reflect_pad1(x), conv pad=1 zeros outside
        ok = (ty >= 0 && ty < HIN + 2 && tx >= 0 && tx < HIN + 2);
        iy = (ty == 0) ? 1 : (ty == HIN + 1 ? HIN - 2 : ty - 1);
        ix = (tx == 0) ? 1 : (tx == HIN + 1 ? HIN - 2 : tx - 1);
      } else {
        ok = (ty >= 0 && ty < HIN && tx >= 0 && tx < HIN);
        iy = ty; ix = tx;
      }
      half8 v;
#pragma unroll
      for (int j = 0; j < 8; ++j) v[j] = (_Float16)0.f;
      if (ok) v = *(const half8*)(actb + ((size_t)iy * HIN + ix) * CIN + cc * 32 + qq * 8);
      smem[e] = v;
    }
    __syncthreads();
    // ---- compute ----
    for (int ky = 0; ky < K; ++ky) {
#pragma unroll
      for (int kx = 0; kx < K; ++kx) {
        const int tap = ky * K + kx;
        half8 a[MR];
#pragma unroll
        for (int mi = 0; mi < MR; ++mi) {
          int co = cob + wc * WCO + mi * 16 + n;
          a[mi] = *(const half8*)(wt + ((size_t)tap * COUT + co) * CIN + cc * 32 + q * 8);
        }
        half8 bf[4];
#pragma unroll
        for (int ni = 0; ni < 4; ++ni) {
          int r = wr * 4 + ni;
          bf[ni] = smem[((r + ky) * 4 + q) * XW + n + kx];
        }
#pragma unroll
        for (int mi = 0; mi < MR; ++mi)
#pragma unroll
          for (int ni = 0; ni < 4; ++ni)
            acc[mi][ni] = __builtin_amdgcn_mfma_f32_16x16x32_f16(a[mi], bf[ni], acc[mi][ni], 0, 0, 0);
      }
    }
  }
  // ---- store NHWC f16 ----
  _Float16* outb = out + (size_t)b * HOUT * HOUT * COUT;
#pragma unroll
  for (int mi = 0; mi < MR; ++mi) {
#pragma unroll
    for (int ni = 0; ni < 4; ++ni) {
      int y = y0 + wr * 4 + ni, x = x0 + n;
      if (y < HOUT && x < HOUT) {
        int co = cob + wc * WCO + mi * 16 + q * 4;
        half4_ h;
#pragma unroll
        for (int j = 0; j < 4; ++j) h[j] = (_Float16)acc[mi][ni][j];
        *(half4_*)(outb + ((size_t)y * HOUT + x) * COUT + co) = h;
      }
    }
  }
}

// ============ zero scratch ============
__global__ void zerok(float* p, int n) {
  int i = blockIdx.x * blockDim.x + threadIdx.x;
  if (i < n) p[i] = 0.f;
}

// ============ per-(b,c) or per-c sums of x and x^2 (NHWC f16, atomic partials) ====
template<int C, bool PERB>
__global__ void statk(const _Float16* __restrict__ x, float* __restrict__ sums, int HW) {
  constexpr int PL = 256 / C;
  int b = blockIdx.z;
  int tid = threadIdx.x;
  int c = tid & (C - 1);
  int pr = tid / C;
  int slab = blockIdx.x, nsl = gridDim.x;
  const _Float16* xb = x + (size_t)b * HW * C;
  float s = 0.f, s2 = 0.f;
  for (int p = slab * PL + pr; p < HW; p += nsl * PL) {
    float v = (float)xb[(size_t)p * C + c];
    s += v; s2 += v * v;
  }
  __shared__ float l1[256], l2[256];
  l1[tid] = s; l2[tid] = s2;
  __syncthreads();
  for (int st = 128; st >= C; st >>= 1) {
    if (tid < st) { l1[tid] += l1[tid + st]; l2[tid] += l2[tid + st]; }
    __syncthreads();
  }
  if (tid < C) {
    int idx = PERB ? b * C + tid : tid;
    atomicAdd(&sums[idx * 2], l1[tid]);
    atomicAdd(&sums[idx * 2 + 1], l2[tid]);
  }
}

// ============ finalize: scale/shift from sums (+optional gamma/beta) ============
__global__ void fink(const float* __restrict__ sums, const float* __restrict__ g,
                     const float* __restrict__ bt, float* __restrict__ scale,
                     float* __restrict__ shift, int cnt, float invn) {
  int i = blockIdx.x * blockDim.x + threadIdx.x;
  if (i >= cnt) return;
  float m = sums[i * 2] * invn;
  float v = sums[i * 2 + 1] * invn - m * m;
  float sc = rsqrtf(v + EPS_);
  if (g) sc *= g[i];
  scale[i] = sc;
  shift[i] = (bt ? bt[i] : 0.f) - m * sc;
}

// ============ apply affine (+relu) in place, NHWC f16, 8c per thread ============
template<int C, bool PERB, bool RELU>
__global__ void applyk(_Float16* __restrict__ x, const float* __restrict__ scale,
                       const float* __restrict__ shift, int HW) {
  constexpr int CG = C / 8;
  size_t idx = (size_t)blockIdx.x * blockDim.x + threadIdx.x;
  size_t tot = (size_t)4 * HW * CG;
  if (idx >= tot) return;
  int cg = (int)(idx % CG);
  size_t bp = idx / CG;
  int b = (int)(bp / HW);
  half8 v = *(half8*)(x + bp * C + cg * 8);
  int base = (PERB ? b * C : 0) + cg * 8;
#pragma unroll
  for (int j = 0; j < 8; ++j) {
    float f = (float)v[j] * scale[base + j] + shift[base + j];
    if (RELU) f = fmaxf(f, 0.f);
    v[j] = (_Float16)f;
  }
  *(half8*)(x + bp * C + cg * 8) = v;
}

// ============ analytic DCT-mean weights w_p ============
// mean_k DCT_ortho(x)_k = (1/N) * sum_p w_p x_p
__global__ void wdctk(float* __restrict__ wd, int N) {
  int i = blockIdx.x * blockDim.x + threadIdx.x;
  if (i >= N) return;
  float Nf = (float)N;
  float c2 = 0.5f * sqrtf(2.f / Nf);
  float a  = sqrtf(1.f / Nf) - c2;
  float phi = PI_ / (4.f * Nf) * (2.f * i + 1.f);
  float cot = cosf(phi) / sinf(phi);
  wd[i] = a + ((i & 1) ? -c2 : c2) * cot;
}

// ============ weighted sum per (b,c): md[b][c] += sum_p wd[p]*x[b,p,c] ============
__global__ void mdctk(const _Float16* __restrict__ x, const float* __restrict__ wd,
                      float* __restrict__ md, int HW) {
  int b = blockIdx.z, tid = threadIdx.x;
  int c = tid & 127, pr = tid >> 7;
  int slab = blockIdx.x, nsl = gridDim.x;
  const _Float16* xb = x + (size_t)b * HW * 128;
  float s = 0.f;
  for (int p = slab * 2 + pr; p < HW; p += nsl * 2)
    s += (float)xb[(size_t)p * 128 + c] * wd[p];
  __shared__ float l1[256];
  l1[tid] = s;
  __syncthreads();
  if (tid < 128) atomicAdd(&md[b * 128 + c], l1[tid] + l1[tid + 128]);
}

// ============ SFOM gate MLP ============
__global__ void gatek(const float* __restrict__ md, const float* __restrict__ w1,
                      const float* __restrict__ w2, float* __restrict__ gate) {
  __shared__ float t1[4][8];
  int tid = threadIdx.x;
  const float invN = 1.f / (float)HW2;
  if (tid < 32) {
    int b = tid >> 3, r = tid & 7;
    float s = 0.f;
    for (int c = 0; c < 128; ++c) s += md[b * 128 + c] * invN * w1[r * 128 + c];
    t1[b][r] = fmaxf(s, 0.f);
  }
  __syncthreads();
  int b = tid >> 7, c = tid & 127;
  float s = 0.f;
#pragma unroll
  for (int r = 0; r < 8; ++r) s += t1[b][r] * w2[c * 8 + r];
  gate[tid] = 1.f / (1.f + expf(-s));
}

// ============ SFOM apply: o = sigmoid(x*(1+g)/2)*x  (NHWC f16) ============
__global__ void sfomk(const _Float16* __restrict__ x, const float* __restrict__ gate,
                      _Float16* __restrict__ o, int HW) {
  size_t idx = (size_t)blockIdx.x * blockDim.x + threadIdx.x;
  size_t tot = (size_t)4 * HW * 16;
  if (idx >= tot) return;
  int cg = (int)(idx % 16);
  size_t bp = idx / 16;
  int b = (int)(bp / HW);
  half8 v = *(const half8*)(x + bp * 128 + cg * 8);
  half8 r;
#pragma unroll
  for (int j = 0; j < 8; ++j) {
    float f = (float)v[j];
    float g = gate[b * 128 + cg * 8 + j];
    float s = 1.f / (1.f + expf(-(f * (1.f + g) * 0.5f)));
    r[j] = (_Float16)(s * f);
  }
  *(half8*)(o + bp * 128 + cg * 8) = r;
}

// ============ sa = sigmoid(1x1 conv 32->1 + b) ============
__global__ void sak(const _Float16* __restrict__ h, const float* __restrict__ cw,
                    const float* __restrict__ cb, float* __restrict__ sa) {
  int idx = blockIdx.x * blockDim.x + threadIdx.x;
  if (idx >= 4 * HW2) return;
  const _Float16* p = h + (size_t)idx * 32;
  float s = cb[0];
#pragma unroll
  for (int c = 0; c < 32; ++c) s += (float)p[c] * cw[c];
  sa[idx] = 1.f / (1.f + expf(-s));
}

// ============ final: NCHW f32 out = sa * O (NHWC f16), LDS transpose ============
__global__ void finalt(const _Float16* __restrict__ o, const float* __restrict__ sa,
                       float* __restrict__ out) {
  __shared__ float t[32][65];
  int b = blockIdx.z, c0 = blockIdx.y * 32, p0 = blockIdx.x * 64;
  int tid = threadIdx.x;
  for (int i = 0; i < 8; ++i) {
    int e = i * 256 + tid; int pl = e >> 5, cl = e & 31;
    int p = p0 + pl;
    if (p < HW2)
      t[cl][pl] = (float)o[((size_t)b * HW2 + p) * 128 + c0 + cl] * sa[b * HW2 + p];
  }
  __syncthreads();
  for (int i = 0; i < 8; ++i) {
    int e = i * 256 + tid; int cl = e >> 6, pl = e & 63;
    int p = p0 + pl;
    if (p < HW2)
      out[((size_t)b * 128 + c0 + cl) * HW2 + p] = t[cl][pl];
  }
}

extern "C" void kernel_launch(void* const* d_in, const int* in_sizes, int n_in,
                              void* d_out, int out_size, void* d_ws, size_t ws_size,
                              hipStream_t stream) {
  const float* x     = (const float*)d_in[0];
  const float* c1w   = (const float*)d_in[1];
  const float* c2w   = (const float*)d_in[3];
  const float* sa_w1 = (const float*)d_in[5];
  const float* sa_w2 = (const float*)d_in[6];
  const float* dw[6] = {(const float*)d_in[7],  (const float*)d_in[10], (const float*)d_in[13],
                        (const float*)d_in[16], (const float*)d_in[19], (const float*)d_in[22]};
  const float* bg[6] = {(const float*)d_in[8],  (const float*)d_in[11], (const float*)d_in[14],
                        (const float*)d_in[17], (const float*)d_in[20], (const float*)d_in[23]};
  const float* bb[6] = {(const float*)d_in[9],  (const float*)d_in[12], (const float*)d_in[15],
                        (const float*)d_in[18], (const float*)d_in[21], (const float*)d_in[24]};
  const float* cw    = (const float*)d_in[25];
  const float* cb    = (const float*)d_in[26];
  float* out = (float*)d_out;

  // ---- workspace carve ----
  char* wsp = (char*)d_ws;
  auto alloc = [&](size_t bytes) { char* p = wsp; wsp += (bytes + 255) & ~(size_t)255; return p; };
  _Float16* B0 = (_Float16*)alloc(NBUF * 2);
  _Float16* B1 = (_Float16*)alloc(NBUF * 2);
  _Float16* B2 = (_Float16*)alloc(NBUF * 2);
  _Float16* B3 = (_Float16*)alloc(NBUF * 2);
  _Float16* wt_c1 = (_Float16*)alloc((size_t)128 * 128 * 9 * 2);
  _Float16* wt_c2 = (_Float16*)alloc((size_t)128 * 128 * 9 * 2);
  const int sci[6] = {128, 32, 64, 128, 128, 64};
  const int sco[6] = {32, 64, 128, 128, 64, 32};
  _Float16* wt_d[6];
  for (int i = 0; i < 6; ++i) wt_d[i] = (_Float16*)alloc((size_t)sco[i] * sci[i] * 49 * 2);
  float* sums  = (float*)alloc(1024 * 4);
  float* scal  = (float*)alloc(512 * 4);
  float* shif  = (float*)alloc(512 * 4);
  float* md    = (float*)alloc(512 * 4);
  float* gate  = (float*)alloc(512 * 4);
  float* wd    = (float*)alloc((size_t)HW2 * 4);
  float* sa    = (float*)alloc((size_t)4 * HW2 * 4);

  // ---- weight prep (ws re-poisoned every call -> redo) ----
  { int t = 128 * 128 * 9;
    wprep<<<(t + 255) / 256, 256, 0, stream>>>(c1w, wt_c1, 128, 128, 3);
    wprep<<<(t + 255) / 256, 256, 0, stream>>>(c2w, wt_c2, 128, 128, 3); }
  for (int i = 0; i < 6; ++i) {
    int t = sco[i] * sci[i] * 49;
    wprep<<<(t + 255) / 256, 256, 0, stream>>>(dw[i], wt_d[i], sco[i], sci[i], 7);
  }

  // ---- input to NHWC f16 ----
  to_nhwc<<<dim3(16384 / 64, 4, 4), 256, 0, stream>>>(x, B0, 128, 16384);

  // ---- conv1 (bias cancels under IN) + IN + relu ----
  conv_mfma<128, 128, 3, 128, 130, true><<<dim3(9 * 17, 2, 4), 256, 0, stream>>>(B0, wt_c1, B1);
  zerok<<<4, 256, 0, stream>>>(sums, 1024);
  statk<128, true><<<dim3(32, 1, 4), 256, 0, stream>>>(B1, sums, HW1);
  fink<<<2, 256, 0, stream>>>(sums, nullptr, nullptr, scal, shif, 512, 1.f / (float)HW1);
  { size_t tot = (size_t)4 * HW1 * 16;
    applyk<128, true, true><<<(int)((tot + 255) / 256), 256, 0, stream>>>(B1, scal, shif, HW1); }

  // ---- conv2 + IN (no relu) ----
  conv_mfma<128, 128, 3, 130, 132, true><<<dim3(9 * 17, 2, 4), 256, 0, stream>>>(B1, wt_c2, B2);
  zerok<<<4, 256, 0, stream>>>(sums, 1024);
  statk<128, true><<<dim3(32, 1, 4), 256, 0, stream>>>(B2, sums, HW2);
  fink<<<2, 256, 0, stream>>>(sums, nullptr, nullptr, scal, shif, 512, 1.f / (float)HW2);
  { size_t tot = (size_t)4 * HW2 * 16;
    applyk<128, true, false><<<(int)((tot + 255) / 256), 256, 0, stream>>>(B2, scal, shif, HW2); }

  // ---- SFOM: analytic DCT-mean -> gate -> apply (idct(g*dct(x)) == g*x) ----
  wdctk<<<(HW2 + 255) / 256, 256, 0, stream>>>(wd, HW2);
  zerok<<<2, 256, 0, stream>>>(md, 512);
  mdctk<<<dim3(64, 1, 4), 256, 0, stream>>>(B2, wd, md, HW2);
  gatek<<<1, 512, 0, stream>>>(md, sa_w1, sa_w2, gate);
  { size_t tot = (size_t)4 * HW2 * 16;
    sfomk<<<(int)((tot + 255) / 256), 256, 0, stream>>>(B2, gate, B3, HW2); }

  // ---- SPEM pyramid: conv7 + BN + relu ----
  // L1: 128->32
  conv_mfma<128, 32, 7, 132, 132, false><<<dim3(9 * 17, 1, 4), 256, 0, stream>>>(B3, wt_d[0], B0);
  zerok<<<4, 256, 0, stream>>>(sums, 1024);
  statk<32, false><<<dim3(32, 1, 4), 256, 0, stream>>>(B0, sums, HW2);
  fink<<<1, 256, 0, stream>>>(sums, bg[0], bb[0], scal, shif, 32, 1.f / (4.f * HW2));
  { size_t tot = (size_t)4 * HW2 * 4;
    applyk<32, false, true><<<(int)((tot + 255) / 256), 256, 0, stream>>>(B0, scal, shif, HW2); }
  // L2: 32->64
  conv_mfma<32, 64, 7, 132, 132, false><<<dim3(9 * 17, 1, 4), 256, 0, stream>>>(B0, wt_d[1], B1);
  zerok<<<4, 256, 0, stream>>>(sums, 1024);
  statk<64, false><<<dim3(32, 1, 4), 256, 0, stream>>>(B1, sums, HW2);
  fink<<<1, 256, 0, stream>>>(sums, bg[1], bb[1], scal, shif, 64, 1.f / (4.f * HW2));
  { size_t tot = (size_t)4 * HW2 * 8;
    applyk<64, false, true><<<(int)((tot + 255) / 256), 256, 0, stream>>>(B1, scal, shif, HW2); }
  // L3: 64->128
  conv_mfma<64, 128, 7, 132, 132, false><<<dim3(9 * 17, 2, 4), 256, 0, stream>>>(B1, wt_d[2], B0);
  zerok<<<4, 256, 0, stream>>>(sums, 1024);
  statk<128, false><<<dim3(32, 1, 4), 256, 0, stream>>>(B0, sums, HW2);
  fink<<<1, 256, 0, stream>>>(sums, bg[2], bb[2], scal, shif, 128, 1.f / (4.f * HW2));
  { size_t tot = (size_t)4 * HW2 * 16;
    applyk<128, false, true><<<(int)((tot + 255) / 256), 256, 0, stream>>>(B0, scal, shif, HW2); }
  // L4: 128->128
  conv_mfma<128, 128, 7, 132, 132, false><<<dim3(9 * 17, 2, 4), 256, 0, stream>>>(B0, wt_d[3], B1);
  zerok<<<4, 256, 0, stream>>>(sums, 1024);
  statk<128, false><<<dim3(32, 1, 4), 256, 0, stream>>>(B1, sums, HW2);
  fink<<<1, 256, 0, stream>>>(sums, bg[3], bb[3], scal, shif, 128, 1.f / (4.f * HW2));
  { size_t tot = (size_t)4 * HW2 * 16;
    applyk<128, false, true><<<(int)((tot + 255) / 256), 256, 0, stream>>>(B1, scal, shif, HW2); }
  // L5: 128->64
  conv_mfma<128, 64, 7, 132, 132, false><<<dim3(9 * 17, 1, 4), 256, 0, stream>>>(B1, wt_d[4], B0);
  zerok<<<4, 256, 0, stream>>>(sums, 1024);
  statk<64, false><<<dim3(32, 1, 4), 256, 0, stream>>>(B0, sums, HW2);
  fink<<<1, 256, 0, stream>>>(sums, bg[4], bb[4], scal, shif, 64, 1.f / (4.f * HW2));
  { size_t tot = (size_t)4 * HW2 * 8;
    applyk<64, false, true><<<(int)((tot + 255) / 256), 256, 0, stream>>>(B0, scal, shif, HW2); }
  // L6: 64->32
  conv_mfma<64, 32, 7, 132, 132, false><<<dim3(9 * 17, 1, 4), 256, 0, stream>>>(B0, wt_d[5], B1);
  zerok<<<4, 256, 0, stream>>>(sums, 1024);
  statk<32, false><<<dim3(32, 1, 4), 256, 0, stream>>>(B1, sums, HW2);
  fink<<<1, 256, 0, stream>>>(sums, bg[5], bb[5], scal, shif, 32, 1.f / (4.f * HW2));
  { size_t tot = (size_t)4 * HW2 * 4;
    applyk<32, false, true><<<(int)((tot + 255) / 256), 256, 0, stream>>>(B1, scal, shif, HW2); }

  // ---- spatial attention + final product (NCHW f32 out) ----
  sak<<<(4 * HW2 + 255) / 256, 256, 0, stream>>>(B1, cw, cb, sa);
  finalt<<<dim3((HW2 + 63) / 64, 4, 4), 256, 0, stream>>>(B3, sa, out);
}

// Round 3
// 1125.056 us; speedup vs baseline: 6.7818x; 1.3279x over previous
//
#include <hip/hip_runtime.h>
#include <math.h>

#define B_    4
#define C_    128
#define HW1   (130*130)
#define HW2   (132*132)
#define NBUF  ((size_t)B_*C_*HW2)
#define EPS_  1e-5f
#define PI_   3.14159265358979f

typedef _Float16 half8 __attribute__((ext_vector_type(8)));
typedef _Float16 half4_ __attribute__((ext_vector_type(4)));
typedef float    float4_ __attribute__((ext_vector_type(4)));

// ============ weight pack: fp32 OIHW -> f16 [cc][tap][g][lane][8] ============
// lane = q*16+n ; co = g*16+n ; ci = cc*32+q*8+j  -> A-frag load is 1KB wave-contiguous
__global__ void wpack_k(const float* __restrict__ src, _Float16* __restrict__ dst,
                        int Cout, int Cin, int K) {
  int idx = blockIdx.x * blockDim.x + threadIdx.x;
  int KK = K * K, COG = Cout / 16;
  int tot = Cout * Cin * KK;
  if (idx >= tot) return;
  int j    = idx & 7;
  int lane = (idx >> 3) & 63;
  int rest = idx >> 9;
  int g    = rest % COG; rest /= COG;
  int tap  = rest % KK;
  int cc   = rest / KK;
  int n = lane & 15, q = lane >> 4;
  int co = g * 16 + n;
  int ci = cc * 32 + q * 8 + j;
  dst[idx] = (_Float16)src[((size_t)co * Cin + ci) * KK + tap];
}

// ============ NCHW f32 -> NHWC f16 (LDS transpose) ============
__global__ void to_nhwc(const float* __restrict__ in, _Float16* __restrict__ out,
                        int C, int HW) {
  __shared__ float t[32][65];
  int b = blockIdx.z, c0 = blockIdx.y * 32, p0 = blockIdx.x * 64;
  int tid = threadIdx.x;
  for (int i = 0; i < 8; ++i) {
    int e = i * 256 + tid; int cl = e >> 6, pl = e & 63;
    int p = p0 + pl;
    float v = 0.f;
    if (p < HW) v = in[((size_t)b * C + c0 + cl) * HW + p];
    t[cl][pl] = v;
  }
  __syncthreads();
  for (int i = 0; i < 8; ++i) {
    int e = i * 256 + tid; int pl = e >> 5, cl = e & 31;
    int p = p0 + pl;
    if (p < HW) out[((size_t)b * HW + p) * C + c0 + cl] = (_Float16)t[cl][pl];
  }
}

// ============ MFMA implicit-GEMM conv, fused input-affine(+relu) ============
// AFF: 0=none, 1=per-(b,c) instance-norm affine, 2=per-c batch-norm affine
template<int CIN, int COUT, int K, int HIN, int HOUT, bool REFLECT, int AFF, bool RELU>
__global__ __launch_bounds__(256) void conv_mfma(
    const _Float16* __restrict__ act, const _Float16* __restrict__ wp,
    const float* __restrict__ scal, const float* __restrict__ shif,
    _Float16* __restrict__ out) {
  constexpr int NWC = (COUT >= 64) ? 2 : 1;
  constexpr int WCO = COUT / NWC;            // 64 / 32 / 32
  constexpr int MR  = WCO / 16;              // 4 / 2 / 2
  constexpr int NWR = 4 / NWC;               // 2 / 2 / 4
  constexpr int ROWS = NWR * 4;              // 8 / 8 / 16
  constexpr int PADc = (K - 1) / 2;
  constexpr int IR = ROWS + K - 1;
  constexpr int XW = 16 + K - 1;
  constexpr int CH = IR * XW * 4;            // 16B chunks, layout (row*XW+x)*4+q
  constexpr int COG = COUT / 16;
  constexpr int KK = K * K;
  constexpr int XT = (HOUT + 15) / 16;

  __shared__ half8 smem[CH];

  const int xt = blockIdx.x % XT, yt = blockIdx.x / XT;
  const int x0 = xt * 16, y0 = yt * ROWS;
  const int b = blockIdx.z;
  const int tid = threadIdx.x;
  const int lane = tid & 63, w = tid >> 6;
  const int wc = (NWC == 2) ? (w & 1) : 0;
  const int wr = (NWC == 2) ? (w >> 1) : w;
  const int n = lane & 15, q = lane >> 4;

  float4_ acc[MR][4];
#pragma unroll
  for (int mi = 0; mi < MR; ++mi)
#pragma unroll
    for (int ni = 0; ni < 4; ++ni)
#pragma unroll
      for (int j = 0; j < 4; ++j) acc[mi][ni][j] = 0.f;

  const _Float16* actb = act + (size_t)b * HIN * HIN * CIN;

  for (int cc = 0; cc < CIN / 32; ++cc) {
    __syncthreads();
    // ---- stage (affine+relu applied; borders stay zero, matching conv zero-pad) ----
    for (int e = tid; e < CH; e += 256) {
      int rx = e >> 2, qq = e & 3;
      int row = rx / XW, lx = rx % XW;
      int ty = y0 + row - PADc;
      int tx = x0 + lx - PADc;
      bool ok; int iy, ix;
      if (REFLECT) {   // P-space; P = reflect_pad1(x), conv pad=1 zeros outside
        ok = (ty >= 0 && ty < HIN + 2 && tx >= 0 && tx < HIN + 2);
        iy = (ty == 0) ? 1 : (ty == HIN + 1 ? HIN - 2 : ty - 1);
        ix = (tx == 0) ? 1 : (tx == HIN + 1 ? HIN - 2 : tx - 1);
      } else {
        ok = (ty >= 0 && ty < HIN && tx >= 0 && tx < HIN);
        iy = ty; ix = tx;
      }
      half8 v;
#pragma unroll
      for (int j = 0; j < 8; ++j) v[j] = (_Float16)0.f;
      if (ok) {
        v = *(const half8*)(actb + ((size_t)iy * HIN + ix) * CIN + cc * 32 + qq * 8);
        if (AFF) {
          int cb2 = (AFF == 1 ? b * CIN : 0) + cc * 32 + qq * 8;
#pragma unroll
          for (int j = 0; j < 8; ++j) {
            float f = (float)v[j] * scal[cb2 + j] + shif[cb2 + j];
            if (RELU) f = fmaxf(f, 0.f);
            v[j] = (_Float16)f;
          }
        }
      }
      smem[e] = v;
    }
    __syncthreads();
    // ---- compute ----
    for (int ky = 0; ky < K; ++ky) {
#pragma unroll
      for (int kx = 0; kx < K; ++kx) {
        const int tap = ky * K + kx;
        half8 a[MR];
#pragma unroll
        for (int mi = 0; mi < MR; ++mi) {
          int g = wc * (WCO / 16) + mi;
          a[mi] = *(const half8*)(wp + (((size_t)(cc * KK + tap) * COG + g) * 64 + lane) * 8);
        }
        half8 bf[4];
#pragma unroll
        for (int ni = 0; ni < 4; ++ni) {
          int r = wr * 4 + ni;
          bf[ni] = smem[((r + ky) * XW + n + kx) * 4 + q];
        }
#pragma unroll
        for (int mi = 0; mi < MR; ++mi)
#pragma unroll
          for (int ni = 0; ni < 4; ++ni)
            acc[mi][ni] = __builtin_amdgcn_mfma_f32_16x16x32_f16(a[mi], bf[ni], acc[mi][ni], 0, 0, 0);
      }
    }
  }
  // ---- store NHWC f16 (raw conv output; norm applied by consumer) ----
  _Float16* outb = out + (size_t)b * HOUT * HOUT * COUT;
#pragma unroll
  for (int mi = 0; mi < MR; ++mi) {
#pragma unroll
    for (int ni = 0; ni < 4; ++ni) {
      int y = y0 + wr * 4 + ni, x = x0 + n;
      if (y < HOUT && x < HOUT) {
        int co = wc * WCO + mi * 16 + q * 4;
        half4_ h;
#pragma unroll
        for (int j = 0; j < 4; ++j) h[j] = (_Float16)acc[mi][ni][j];
        *(half4_*)(outb + ((size_t)y * HOUT + x) * COUT + co) = h;
      }
    }
  }
}

// ============ zero scratch ============
__global__ void zerok(float* p, int n) {
  int i = blockIdx.x * blockDim.x + threadIdx.x;
  if (i < n) p[i] = 0.f;
}

// ============ per-(b,c) or per-c sums of x, x^2 (NHWC f16, atomic partials) ====
template<int C, bool PERB>
__global__ void statk(const _Float16* __restrict__ x, float* __restrict__ sums, int HW) {
  constexpr int PL = 256 / C;
  int b = blockIdx.z;
  int tid = threadIdx.x;
  int c = tid & (C - 1);
  int pr = tid / C;
  int slab = blockIdx.x, nsl = gridDim.x;
  const _Float16* xb = x + (size_t)b * HW * C;
  float s = 0.f, s2 = 0.f;
  for (int p = slab * PL + pr; p < HW; p += nsl * PL) {
    float v = (float)xb[(size_t)p * C + c];
    s += v; s2 += v * v;
  }
  __shared__ float l1[256], l2[256];
  l1[tid] = s; l2[tid] = s2;
  __syncthreads();
  for (int st = 128; st >= C; st >>= 1) {
    if (tid < st) { l1[tid] += l1[tid + st]; l2[tid] += l2[tid + st]; }
    __syncthreads();
  }
  if (tid < C) {
    int idx = PERB ? b * C + tid : tid;
    atomicAdd(&sums[idx * 2], l1[tid]);
    atomicAdd(&sums[idx * 2 + 1], l2[tid]);
  }
}

// ============ finalize scale/shift ============
__global__ void fink(const float* __restrict__ sums, const float* __restrict__ g,
                     const float* __restrict__ bt, float* __restrict__ scale,
                     float* __restrict__ shift, int cnt, float invn) {
  int i = blockIdx.x * blockDim.x + threadIdx.x;
  if (i >= cnt) return;
  float m = sums[i * 2] * invn;
  float v = sums[i * 2 + 1] * invn - m * m;
  float sc = rsqrtf(v + EPS_);
  if (g) sc *= g[i];
  scale[i] = sc;
  shift[i] = (bt ? bt[i] : 0.f) - m * sc;
}

// ============ analytic DCT-mean weights ============
__global__ void wdctk(float* __restrict__ wd, int N) {
  int i = blockIdx.x * blockDim.x + threadIdx.x;
  if (i >= N) return;
  float Nf = (float)N;
  float c2 = 0.5f * sqrtf(2.f / Nf);
  float a  = sqrtf(1.f / Nf) - c2;
  float phi = PI_ / (4.f * Nf) * (2.f * i + 1.f);
  float cot = cosf(phi) / sinf(phi);
  wd[i] = a + ((i & 1) ? -c2 : c2) * cot;
}

// ============ md[b][c] += sum_p wd[p]*(sc*x+sh)  (x raw conv2 out) ============
__global__ void mdctk(const _Float16* __restrict__ x, const float* __restrict__ wd,
                      const float* __restrict__ scal, const float* __restrict__ shif,
                      float* __restrict__ md, int HW) {
  int b = blockIdx.z, tid = threadIdx.x;
  int c = tid & 127, pr = tid >> 7;
  int slab = blockIdx.x, nsl = gridDim.x;
  const _Float16* xb = x + (size_t)b * HW * 128;
  float sc = scal[b * 128 + c], sh = shif[b * 128 + c];
  float s = 0.f;
  for (int p = slab * 2 + pr; p < HW; p += nsl * 2)
    s += ((float)xb[(size_t)p * 128 + c] * sc + sh) * wd[p];
  __shared__ float l1[256];
  l1[tid] = s;
  __syncthreads();
  if (tid < 128) atomicAdd(&md[b * 128 + c], l1[tid] + l1[tid + 128]);
}

// ============ SFOM gate MLP ============
__global__ void gatek(const float* __restrict__ md, const float* __restrict__ w1,
                      const float* __restrict__ w2, float* __restrict__ gate) {
  __shared__ float t1[4][8];
  int tid = threadIdx.x;
  const float invN = 1.f / (float)HW2;
  if (tid < 32) {
    int b = tid >> 3, r = tid & 7;
    float s = 0.f;
    for (int c = 0; c < 128; ++c) s += md[b * 128 + c] * invN * w1[r * 128 + c];
    t1[b][r] = fmaxf(s, 0.f);
  }
  __syncthreads();
  int b = tid >> 7, c = tid & 127;
  float s = 0.f;
#pragma unroll
  for (int r = 0; r < 8; ++r) s += t1[b][r] * w2[c * 8 + r];
  gate[tid] = 1.f / (1.f + expf(-s));
}

// ============ SFOM apply on raw conv2: xn = sc*x+sh; o = sigmoid(xn*(1+g)/2)*xn ====
__global__ void sfomk(const _Float16* __restrict__ x, const float* __restrict__ scal,
                      const float* __restrict__ shif, const float* __restrict__ gate,
                      _Float16* __restrict__ o, int HW) {
  size_t idx = (size_t)blockIdx.x * blockDim.x + threadIdx.x;
  size_t tot = (size_t)4 * HW * 16;
  if (idx >= tot) return;
  int cg = (int)(idx % 16);
  size_t bp = idx / 16;
  int b = (int)(bp / HW);
  half8 v = *(const half8*)(x + bp * 128 + cg * 8);
  half8 r;
#pragma unroll
  for (int j = 0; j < 8; ++j) {
    int c = cg * 8 + j;
    float f = (float)v[j] * scal[b * 128 + c] + shif[b * 128 + c];
    float g = gate[b * 128 + c];
    float s = 1.f / (1.f + expf(-(f * (1.f + g) * 0.5f)));
    r[j] = (_Float16)(s * f);
  }
  *(half8*)(o + bp * 128 + cg * 8) = r;
}

// ============ sa = sigmoid(b + sum_c cw[c]*relu(sc*h+sh))  (h = raw L6 out) ====
__global__ void sak(const _Float16* __restrict__ h, const float* __restrict__ scal,
                    const float* __restrict__ shif, const float* __restrict__ cw,
                    const float* __restrict__ cb, float* __restrict__ sa) {
  int idx = blockIdx.x * blockDim.x + threadIdx.x;
  if (idx >= 4 * HW2) return;
  const _Float16* p = h + (size_t)idx * 32;
  float s = cb[0];
#pragma unroll
  for (int c = 0; c < 32; ++c) {
    float v = fmaxf((float)p[c] * scal[c] + shif[c], 0.f);
    s += v * cw[c];
  }
  sa[idx] = 1.f / (1.f + expf(-s));
}

// ============ final: NCHW f32 out = sa * O (NHWC f16), LDS transpose ============
__global__ void finalt(const _Float16* __restrict__ o, const float* __restrict__ sa,
                       float* __restrict__ out) {
  __shared__ float t[32][65];
  int b = blockIdx.z, c0 = blockIdx.y * 32, p0 = blockIdx.x * 64;
  int tid = threadIdx.x;
  for (int i = 0; i < 8; ++i) {
    int e = i * 256 + tid; int pl = e >> 5, cl = e & 31;
    int p = p0 + pl;
    if (p < HW2)
      t[cl][pl] = (float)o[((size_t)b * HW2 + p) * 128 + c0 + cl] * sa[b * HW2 + p];
  }
  __syncthreads();
  for (int i = 0; i < 8; ++i) {
    int e = i * 256 + tid; int cl = e >> 6, pl = e & 63;
    int p = p0 + pl;
    if (p < HW2)
      out[((size_t)b * 128 + c0 + cl) * HW2 + p] = t[cl][pl];
  }
}

extern "C" void kernel_launch(void* const* d_in, const int* in_sizes, int n_in,
                              void* d_out, int out_size, void* d_ws, size_t ws_size,
                              hipStream_t stream) {
  const float* x     = (const float*)d_in[0];
  const float* c1w   = (const float*)d_in[1];
  const float* c2w   = (const float*)d_in[3];
  const float* sa_w1 = (const float*)d_in[5];
  const float* sa_w2 = (const float*)d_in[6];
  const float* dw[6] = {(const float*)d_in[7],  (const float*)d_in[10], (const float*)d_in[13],
                        (const float*)d_in[16], (const float*)d_in[19], (const float*)d_in[22]};
  const float* bg[6] = {(const float*)d_in[8],  (const float*)d_in[11], (const float*)d_in[14],
                        (const float*)d_in[17], (const float*)d_in[20], (const float*)d_in[23]};
  const float* bb[6] = {(const float*)d_in[9],  (const float*)d_in[12], (const float*)d_in[15],
                        (const float*)d_in[18], (const float*)d_in[21], (const float*)d_in[24]};
  const float* cw    = (const float*)d_in[25];
  const float* cb    = (const float*)d_in[26];
  float* out = (float*)d_out;

  // ---- workspace carve ----
  char* wsp = (char*)d_ws;
  auto alloc = [&](size_t bytes) { char* p = wsp; wsp += (bytes + 255) & ~(size_t)255; return p; };
  _Float16* B0 = (_Float16*)alloc(NBUF * 2);
  _Float16* B1 = (_Float16*)alloc(NBUF * 2);
  _Float16* B2 = (_Float16*)alloc(NBUF * 2);
  _Float16* B3 = (_Float16*)alloc(NBUF * 2);
  _Float16* wp_c1 = (_Float16*)alloc((size_t)128 * 128 * 9 * 2);
  _Float16* wp_c2 = (_Float16*)alloc((size_t)128 * 128 * 9 * 2);
  const int sci[6] = {128, 32, 64, 128, 128, 64};
  const int sco[6] = {32, 64, 128, 128, 64, 32};
  _Float16* wp_d[6];
  for (int i = 0; i < 6; ++i) wp_d[i] = (_Float16*)alloc((size_t)sco[i] * sci[i] * 49 * 2);
  float* sums  = (float*)alloc(1024 * 4);
  float* scal  = (float*)alloc(512 * 4);
  float* shif  = (float*)alloc(512 * 4);
  float* md    = (float*)alloc(512 * 4);
  float* gate  = (float*)alloc(512 * 4);
  float* wd    = (float*)alloc((size_t)HW2 * 4);
  float* sa    = (float*)alloc((size_t)4 * HW2 * 4);

  // ---- weight pack (ws re-poisoned each call -> redo) ----
  { int t = 128 * 128 * 9;
    wpack_k<<<(t + 255) / 256, 256, 0, stream>>>(c1w, wp_c1, 128, 128, 3);
    wpack_k<<<(t + 255) / 256, 256, 0, stream>>>(c2w, wp_c2, 128, 128, 3); }
  for (int i = 0; i < 6; ++i) {
    int t = sco[i] * sci[i] * 49;
    wpack_k<<<(t + 255) / 256, 256, 0, stream>>>(dw[i], wp_d[i], sco[i], sci[i], 7);
  }

  // ---- input to NHWC f16 ----
  to_nhwc<<<dim3(16384 / 64, 4, 4), 256, 0, stream>>>(x, B0, 128, 16384);

  // ---- conv1 (bias cancels under IN); stats for IN+relu ----
  conv_mfma<128, 128, 3, 128, 130, true, 0, false><<<dim3(9 * 17, 1, 4), 256, 0, stream>>>(
      B0, wp_c1, nullptr, nullptr, B1);
  zerok<<<4, 256, 0, stream>>>(sums, 1024);
  statk<128, true><<<dim3(32, 1, 4), 256, 0, stream>>>(B1, sums, HW1);
  fink<<<2, 256, 0, stream>>>(sums, nullptr, nullptr, scal, shif, 512, 1.f / (float)HW1);

  // ---- conv2 (stages IN(conv1)+relu); stats for conv2's IN ----
  conv_mfma<128, 128, 3, 130, 132, true, 1, true><<<dim3(9 * 17, 1, 4), 256, 0, stream>>>(
      B1, wp_c2, scal, shif, B2);
  zerok<<<4, 256, 0, stream>>>(sums, 1024);
  statk<128, true><<<dim3(32, 1, 4), 256, 0, stream>>>(B2, sums, HW2);
  fink<<<2, 256, 0, stream>>>(sums, nullptr, nullptr, scal, shif, 512, 1.f / (float)HW2);

  // ---- SFOM: analytic DCT-mean -> gate -> apply (idct(g*dct(x)) == g*x) ----
  wdctk<<<(HW2 + 255) / 256, 256, 0, stream>>>(wd, HW2);
  zerok<<<2, 256, 0, stream>>>(md, 512);
  mdctk<<<dim3(64, 1, 4), 256, 0, stream>>>(B2, wd, scal, shif, md, HW2);
  gatek<<<1, 512, 0, stream>>>(md, sa_w1, sa_w2, gate);
  { size_t tot = (size_t)4 * HW2 * 16;
    sfomk<<<(int)((tot + 255) / 256), 256, 0, stream>>>(B2, scal, shif, gate, B3, HW2); }

  // ---- SPEM pyramid: conv7 (BN+relu of previous fused into staging) ----
  // L1: 128->32 (input B3 already activated)
  conv_mfma<128, 32, 7, 132, 132, false, 0, false><<<dim3(9 * 9, 1, 4), 256, 0, stream>>>(
      B3, wp_d[0], nullptr, nullptr, B0);
  zerok<<<4, 256, 0, stream>>>(sums, 1024);
  statk<32, false><<<dim3(32, 1, 4), 256, 0, stream>>>(B0, sums, HW2);
  fink<<<1, 256, 0, stream>>>(sums, bg[0], bb[0], scal, shif, 32, 1.f / (4.f * HW2));
  // L2: 32->64
  conv_mfma<32, 64, 7, 132, 132, false, 2, true><<<dim3(9 * 17, 1, 4), 256, 0, stream>>>(
      B0, wp_d[1], scal, shif, B1);
  zerok<<<4, 256, 0, stream>>>(sums, 1024);
  statk<64, false><<<dim3(32, 1, 4), 256, 0, stream>>>(B1, sums, HW2);
  fink<<<1, 256, 0, stream>>>(sums, bg[1], bb[1], scal, shif, 64, 1.f / (4.f * HW2));
  // L3: 64->128
  conv_mfma<64, 128, 7, 132, 132, false, 2, true><<<dim3(9 * 17, 1, 4), 256, 0, stream>>>(
      B1, wp_d[2], scal, shif, B0);
  zerok<<<4, 256, 0, stream>>>(sums, 1024);
  statk<128, false><<<dim3(32, 1, 4), 256, 0, stream>>>(B0, sums, HW2);
  fink<<<1, 256, 0, stream>>>(sums, bg[2], bb[2], scal, shif, 128, 1.f / (4.f * HW2));
  // L4: 128->128
  conv_mfma<128, 128, 7, 132, 132, false, 2, true><<<dim3(9 * 17, 1, 4), 256, 0, stream>>>(
      B0, wp_d[3], scal, shif, B1);
  zerok<<<4, 256, 0, stream>>>(sums, 1024);
  statk<128, false><<<dim3(32, 1, 4), 256, 0, stream>>>(B1, sums, HW2);
  fink<<<1, 256, 0, stream>>>(sums, bg[3], bb[3], scal, shif, 128, 1.f / (4.f * HW2));
  // L5: 128->64
  conv_mfma<128, 64, 7, 132, 132, false, 2, true><<<dim3(9 * 17, 1, 4), 256, 0, stream>>>(
      B1, wp_d[4], scal, shif, B0);
  zerok<<<4, 256, 0, stream>>>(sums, 1024);
  statk<64, false><<<dim3(32, 1, 4), 256, 0, stream>>>(B0, sums, HW2);
  fink<<<1, 256, 0, stream>>>(sums, bg[4], bb[4], scal, shif, 64, 1.f / (4.f * HW2));
  // L6: 64->32
  conv_mfma<64, 32, 7, 132, 132, false, 2, true><<<dim3(9 * 9, 1, 4), 256, 0, stream>>>(
      B0, wp_d[5], scal, shif, B1);
  zerok<<<4, 256, 0, stream>>>(sums, 1024);
  statk<32, false><<<dim3(32, 1, 4), 256, 0, stream>>>(B1, sums, HW2);
  fink<<<1, 256, 0, stream>>>(sums, bg[5], bb[5], scal, shif, 32, 1.f / (4.f * HW2));

  // ---- spatial attention (BN+relu fused) + final product (NCHW f32 out) ----
  sak<<<(4 * HW2 + 255) / 256, 256, 0, stream>>>(B1, scal, shif, cw, cb, sa);
  finalt<<<dim3((HW2 + 63) / 64, 4, 4), 256, 0, stream>>>(B3, sa, out);
}

// Round 4
// 733.745 us; speedup vs baseline: 10.3986x; 1.5333x over previous
//
#include <hip/hip_runtime.h>
#include <math.h>

#define B_    4
#define HW1   (130*130)
#define HW2   (132*132)
#define NBUF  ((size_t)B_*128*HW2)
#define EPS_  1e-5f
#define PI_   3.14159265358979f

typedef _Float16 half8 __attribute__((ext_vector_type(8)));
typedef _Float16 half4_ __attribute__((ext_vector_type(4)));
typedef float    float4_ __attribute__((ext_vector_type(4)));

// ============ batched weight pack: fp32 OIHW -> f16 [cc][tap][g][lane][8] ====
// lane=q*16+n ; co=g*16+n ; ci=cc*32+q*8+j  -> A-frag load is 1KB wave-contiguous
struct WPackArgs {
  const float* src[8];
  _Float16*    dst[8];
  int cout[8], cin[8], kk[8];
  int off[9];
};
__global__ void wpack_all(WPackArgs p) {
  int idx = blockIdx.x * blockDim.x + threadIdx.x;
  if (idx >= p.off[8]) return;
  int s = 0;
  while (idx >= p.off[s + 1]) ++s;
  int i = idx - p.off[s];
  int Cin = p.cin[s], K = p.kk[s];
  int KK = K * K, COG = p.cout[s] / 16;
  int j    = i & 7;
  int lane = (i >> 3) & 63;
  int rest = i >> 9;
  int g    = rest % COG; rest /= COG;
  int tap  = rest % KK;
  int cc   = rest / KK;
  int n = lane & 15, q = lane >> 4;
  int co = g * 16 + n;
  int ci = cc * 32 + q * 8 + j;
  p.dst[s][i] = (_Float16)p.src[s][((size_t)co * Cin + ci) * KK + tap];
}

// ============ NCHW f32 -> NHWC f16 (LDS transpose) ============
__global__ void to_nhwc(const float* __restrict__ in, _Float16* __restrict__ out,
                        int C, int HW) {
  __shared__ float t[32][65];
  int b = blockIdx.z, c0 = blockIdx.y * 32, p0 = blockIdx.x * 64;
  int tid = threadIdx.x;
  for (int i = 0; i < 8; ++i) {
    int e = i * 256 + tid; int cl = e >> 6, pl = e & 63;
    int p = p0 + pl;
    float v = 0.f;
    if (p < HW) v = in[((size_t)b * C + c0 + cl) * HW + p];
    t[cl][pl] = v;
  }
  __syncthreads();
  for (int i = 0; i < 8; ++i) {
    int e = i * 256 + tid; int pl = e >> 5, cl = e & 31;
    int p = p0 + pl;
    if (p < HW) out[((size_t)b * HW + p) * C + c0 + cl] = (_Float16)t[cl][pl];
  }
}

__global__ void zerok(float* p, int n) {
  int i = blockIdx.x * blockDim.x + threadIdx.x;
  if (i < n) p[i] = 0.f;
}

// ============ MFMA implicit-GEMM conv ============
// - input affine(+relu) computed INLINE from raw sums (AFF:0 none,1 per-(b,c),2 per-c BN)
// - output per-co stats (sum, sumsq over valid spatial) accumulated to sums_out
// - LDS layout [row][q][x]: frag reads AND staging writes are 8-lane 16B-contiguous
//   (conflict-free); A/B frags double-buffered across taps (prefetch 1 tap ahead)
template<int CIN, int COUT, int K, int HIN, int HOUT, bool REFLECT, int AFF, bool RELU, bool POB>
__global__ __launch_bounds__(256, 2) void conv_mfma(
    const _Float16* __restrict__ act, const _Float16* __restrict__ wp,
    const float* __restrict__ sums_in, const float* __restrict__ gam,
    const float* __restrict__ bet, float invn, float* __restrict__ sums_out,
    _Float16* __restrict__ out) {
  constexpr int NWC = (COUT >= 64) ? 2 : 1;
  constexpr int WCO = COUT / NWC;            // 64 / 32 / 32
  constexpr int MR  = WCO / 16;              // 4 / 2 / 2
  constexpr int NWR = 4 / NWC;               // 2 / 2 / 4
  constexpr int ROWS = NWR * 4;              // 8 / 8 / 16
  constexpr int PADc = (K - 1) / 2;
  constexpr int IR = ROWS + K - 1;
  constexpr int XW = 16 + K - 1;
  constexpr int CH = IR * 4 * XW;            // 16B chunks, idx (row*4+q)*XW+x
  constexpr int COG = COUT / 16;
  constexpr int KK = K * K;
  constexpr int XT = (HOUT + 15) / 16;

  __shared__ half8 smem[CH];
  __shared__ float2 snorm[CIN];
  __shared__ float bsum[COUT * 2];

  const int xt = blockIdx.x % XT, yt = blockIdx.x / XT;
  const int x0 = xt * 16, y0 = yt * ROWS;
  const int b = blockIdx.z;
  const int tid = threadIdx.x;
  const int lane = tid & 63, w = tid >> 6;
  const int wc = (NWC == 2) ? (w & 1) : 0;
  const int wr = (NWC == 2) ? (w >> 1) : w;
  const int n = lane & 15, q = lane >> 4;

  // ---- preamble: inline norm params + zero block stats ----
  if (AFF) {
    if (tid < CIN) {
      int idx = (AFF == 1 ? b * CIN : 0) + tid;
      float m  = sums_in[idx * 2] * invn;
      float vr = sums_in[idx * 2 + 1] * invn - m * m;
      float sc = rsqrtf(vr + EPS_);
      if (AFF == 2) sc *= gam[tid];
      float sh = (AFF == 2 ? bet[tid] : 0.f) - m * sc;
      snorm[tid] = make_float2(sc, sh);
    }
  }
  if (tid < COUT) { bsum[tid * 2] = 0.f; bsum[tid * 2 + 1] = 0.f; }

  float4_ acc[MR][4];
#pragma unroll
  for (int mi = 0; mi < MR; ++mi)
#pragma unroll
    for (int ni = 0; ni < 4; ++ni)
#pragma unroll
      for (int j = 0; j < 4; ++j) acc[mi][ni][j] = 0.f;

  const _Float16* actb = act + (size_t)b * HIN * HIN * CIN;

  for (int cc = 0; cc < CIN / 32; ++cc) {
    __syncthreads();
    // ---- per-thread norm regs (qq = tid&3 fixed across staging elements) ----
    float nsc[8], nsh[8];
    if (AFF) {
      int cb2 = cc * 32 + (tid & 3) * 8;
#pragma unroll
      for (int j = 0; j < 8; ++j) { float2 t = snorm[cb2 + j]; nsc[j] = t.x; nsh[j] = t.y; }
    }
    // ---- stage (affine+relu applied; borders stay zero = conv zero-pad) ----
    for (int e = tid; e < CH; e += 256) {
      int qq = e & 3, rx = e >> 2;
      int row = rx / XW, lx = rx % XW;
      int ty = y0 + row - PADc;
      int tx = x0 + lx - PADc;
      bool ok; int iy, ix;
      if (REFLECT) {   // P-space; P = reflect_pad1(x), conv pad=1 zeros outside
        ok = (ty >= 0 && ty < HIN + 2 && tx >= 0 && tx < HIN + 2);
        iy = (ty == 0) ? 1 : (ty == HIN + 1 ? HIN - 2 : ty - 1);
        ix = (tx == 0) ? 1 : (tx == HIN + 1 ? HIN - 2 : tx - 1);
      } else {
        ok = (ty >= 0 && ty < HIN && tx >= 0 && tx < HIN);
        iy = ty; ix = tx;
      }
      half8 v;
#pragma unroll
      for (int j = 0; j < 8; ++j) v[j] = (_Float16)0.f;
      if (ok) {
        v = *(const half8*)(actb + ((size_t)iy * HIN + ix) * CIN + cc * 32 + qq * 8);
        if (AFF) {
#pragma unroll
          for (int j = 0; j < 8; ++j) {
            float f = (float)v[j] * nsc[j] + nsh[j];
            if (RELU) f = fmaxf(f, 0.f);
            v[j] = (_Float16)f;
          }
        }
      }
      smem[(row * 4 + qq) * XW + lx] = v;
    }
    __syncthreads();
    // ---- compute: taps double-buffered (prefetch A from global, B from LDS) ----
    auto ldA = [&](int tap, half8* a) {
#pragma unroll
      for (int mi = 0; mi < MR; ++mi) {
        int g = wc * MR + mi;
        a[mi] = *(const half8*)(wp + (((size_t)(cc * KK + tap) * COG + g) * 64 + lane) * 8);
      }
    };
    auto ldB = [&](int tap, half8* c) {
      int ky = tap / K, kx = tap % K;
#pragma unroll
      for (int ni = 0; ni < 4; ++ni)
        c[ni] = smem[((wr * 4 + ni + ky) * 4 + q) * XW + n + kx];
    };
    auto domf = [&](half8* a, half8* c) {
#pragma unroll
      for (int mi = 0; mi < MR; ++mi)
#pragma unroll
        for (int ni = 0; ni < 4; ++ni)
          acc[mi][ni] = __builtin_amdgcn_mfma_f32_16x16x32_f16(a[mi], c[ni], acc[mi][ni], 0, 0, 0);
    };
    half8 a0[MR], a1[MR], c0[4], c1[4];
    ldA(0, a0); ldB(0, c0);
    for (int tap = 0; tap + 1 < KK; tap += 2) {   // KK odd: tap+2 <= KK-1 inside
      ldA(tap + 1, a1); ldB(tap + 1, c1);
      domf(a0, c0);
      ldA(tap + 2, a0); ldB(tap + 2, c0);
      domf(a1, c1);
    }
    domf(a0, c0);                                  // tap KK-1
  }

  // ---- epilogue 1: per-co stats from f32 accumulators ----
  const bool xv = (x0 + n) < HOUT;
#pragma unroll
  for (int mi = 0; mi < MR; ++mi) {
#pragma unroll
    for (int j = 0; j < 4; ++j) {
      float s = 0.f, s2 = 0.f;
#pragma unroll
      for (int ni = 0; ni < 4; ++ni) {
        int y = y0 + wr * 4 + ni;
        float f = acc[mi][ni][j];
        bool v = xv && (y < HOUT);
        s  += v ? f : 0.f;
        s2 += v ? f * f : 0.f;
      }
#pragma unroll
      for (int off = 1; off < 16; off <<= 1) {    // reduce across the 16 n-lanes
        s  += __shfl_xor(s,  off, 64);
        s2 += __shfl_xor(s2, off, 64);
      }
      if (n == 0) {
        int co = wc * WCO + mi * 16 + q * 4 + j;
        atomicAdd(&bsum[co * 2],     s);
        atomicAdd(&bsum[co * 2 + 1], s2);
      }
    }
  }
  // ---- epilogue 2: store NHWC f16 (raw conv out; norm applied by consumer) ----
  _Float16* outb = out + (size_t)b * HOUT * HOUT * COUT;
#pragma unroll
  for (int mi = 0; mi < MR; ++mi) {
#pragma unroll
    for (int ni = 0; ni < 4; ++ni) {
      int y = y0 + wr * 4 + ni, x = x0 + n;
      if (y < HOUT && x < HOUT) {
        int co = wc * WCO + mi * 16 + q * 4;
        half4_ h;
#pragma unroll
        for (int j = 0; j < 4; ++j) h[j] = (_Float16)acc[mi][ni][j];
        *(half4_*)(outb + ((size_t)y * HOUT + x) * COUT + co) = h;
      }
    }
  }
  __syncthreads();
  if (tid < COUT) {
    int idx = (POB ? b * COUT : 0) + tid;
    atomicAdd(&sums_out[idx * 2],     bsum[tid * 2]);
    atomicAdd(&sums_out[idx * 2 + 1], bsum[tid * 2 + 1]);
  }
}

// ============ analytic DCT-mean weights ============
__global__ void wdctk(float* __restrict__ wd, int N) {
  int i = blockIdx.x * blockDim.x + threadIdx.x;
  if (i >= N) return;
  float Nf = (float)N;
  float c2 = 0.5f * sqrtf(2.f / Nf);
  float a  = sqrtf(1.f / Nf) - c2;
  float phi = PI_ / (4.f * Nf) * (2.f * i + 1.f);
  float cot = cosf(phi) / sinf(phi);
  wd[i] = a + ((i & 1) ? -c2 : c2) * cot;
}

// ============ md[b][c] += sum_p wd[p]*IN(x)  (inline norm from sums2) ============
__global__ void mdctk(const _Float16* __restrict__ x, const float* __restrict__ wd,
                      const float* __restrict__ sums2, float invn,
                      float* __restrict__ md, int HW) {
  int b = blockIdx.z, tid = threadIdx.x;
  int c = tid & 127, pr = tid >> 7;
  int slab = blockIdx.x, nsl = gridDim.x;
  float m  = sums2[(b * 128 + c) * 2] * invn;
  float sc = rsqrtf(sums2[(b * 128 + c) * 2 + 1] * invn - m * m + EPS_);
  float sh = -m * sc;
  const _Float16* xb = x + (size_t)b * HW * 128;
  float s = 0.f;
  for (int p = slab * 2 + pr; p < HW; p += nsl * 2)
    s += ((float)xb[(size_t)p * 128 + c] * sc + sh) * wd[p];
  __shared__ float l1[256];
  l1[tid] = s;
  __syncthreads();
  if (tid < 128) atomicAdd(&md[b * 128 + c], l1[tid] + l1[tid + 128]);
}

// ============ SFOM gate MLP ============
__global__ void gatek(const float* __restrict__ md, const float* __restrict__ w1,
                      const float* __restrict__ w2, float* __restrict__ gate) {
  __shared__ float t1[4][8];
  int tid = threadIdx.x;
  const float invN = 1.f / (float)HW2;
  if (tid < 32) {
    int b = tid >> 3, r = tid & 7;
    float s = 0.f;
    for (int c = 0; c < 128; ++c) s += md[b * 128 + c] * invN * w1[r * 128 + c];
    t1[b][r] = fmaxf(s, 0.f);
  }
  __syncthreads();
  int b = tid >> 7, c = tid & 127;
  float s = 0.f;
#pragma unroll
  for (int r = 0; r < 8; ++r) s += t1[b][r] * w2[c * 8 + r];
  gate[tid] = 1.f / (1.f + expf(-s));
}

// ============ SFOM apply: xn = IN(x); o = sigmoid(xn*(1+g)/2)*xn ============
__global__ void sfomk(const _Float16* __restrict__ x, const float* __restrict__ sums2,
                      float invn, const float* __restrict__ gate,
                      _Float16* __restrict__ o, int HW) {
  size_t idx = (size_t)blockIdx.x * blockDim.x + threadIdx.x;
  size_t tot = (size_t)4 * HW * 16;
  if (idx >= tot) return;
  int cg = (int)(idx % 16);
  size_t bp = idx / 16;
  int b = (int)(bp / HW);
  half8 v = *(const half8*)(x + bp * 128 + cg * 8);
  half8 r;
#pragma unroll
  for (int j = 0; j < 8; ++j) {
    int c = cg * 8 + j;
    float m  = sums2[(b * 128 + c) * 2] * invn;
    float sc = rsqrtf(sums2[(b * 128 + c) * 2 + 1] * invn - m * m + EPS_);
    float f = (float)v[j] * sc - m * sc;
    float g = gate[b * 128 + c];
    float s = 1.f / (1.f + expf(-(f * (1.f + g) * 0.5f)));
    r[j] = (_Float16)(s * f);
  }
  *(half8*)(o + bp * 128 + cg * 8) = r;
}

// ============ sa = sigmoid(b + sum_c cw[c]*relu(BN(h)))  (inline from sums6) ====
__global__ void sak(const _Float16* __restrict__ h, const float* __restrict__ sums6,
                    float invn, const float* __restrict__ gam, const float* __restrict__ bet,
                    const float* __restrict__ cw, const float* __restrict__ cb,
                    float* __restrict__ sa) {
  __shared__ float ssc[32], ssh[32];
  int tid = threadIdx.x;
  if (tid < 32) {
    float m  = sums6[tid * 2] * invn;
    float sc = rsqrtf(sums6[tid * 2 + 1] * invn - m * m + EPS_) * gam[tid];
    ssc[tid] = sc;
    ssh[tid] = bet[tid] - m * sc;
  }
  __syncthreads();
  int idx = blockIdx.x * blockDim.x + tid;
  if (idx >= 4 * HW2) return;
  const _Float16* p = h + (size_t)idx * 32;
  float s = cb[0];
#pragma unroll
  for (int c = 0; c < 32; ++c)
    s += fmaxf((float)p[c] * ssc[c] + ssh[c], 0.f) * cw[c];
  sa[idx] = 1.f / (1.f + expf(-s));
}

// ============ final: NCHW f32 out = sa * O (NHWC f16), LDS transpose ============
__global__ void finalt(const _Float16* __restrict__ o, const float* __restrict__ sa,
                       float* __restrict__ out) {
  __shared__ float t[32][65];
  int b = blockIdx.z, c0 = blockIdx.y * 32, p0 = blockIdx.x * 64;
  int tid = threadIdx.x;
  for (int i = 0; i < 8; ++i) {
    int e = i * 256 + tid; int pl = e >> 5, cl = e & 31;
    int p = p0 + pl;
    if (p < HW2)
      t[cl][pl] = (float)o[((size_t)b * HW2 + p) * 128 + c0 + cl] * sa[b * HW2 + p];
  }
  __syncthreads();
  for (int i = 0; i < 8; ++i) {
    int e = i * 256 + tid; int cl = e >> 6, pl = e & 63;
    int p = p0 + pl;
    if (p < HW2)
      out[((size_t)b * 128 + c0 + cl) * HW2 + p] = t[cl][pl];
  }
}

extern "C" void kernel_launch(void* const* d_in, const int* in_sizes, int n_in,
                              void* d_out, int out_size, void* d_ws, size_t ws_size,
                              hipStream_t stream) {
  const float* x     = (const float*)d_in[0];
  const float* c1w   = (const float*)d_in[1];
  const float* c2w   = (const float*)d_in[3];
  const float* sa_w1 = (const float*)d_in[5];
  const float* sa_w2 = (const float*)d_in[6];
  const float* dw[6] = {(const float*)d_in[7],  (const float*)d_in[10], (const float*)d_in[13],
                        (const float*)d_in[16], (const float*)d_in[19], (const float*)d_in[22]};
  const float* bg[6] = {(const float*)d_in[8],  (const float*)d_in[11], (const float*)d_in[14],
                        (const float*)d_in[17], (const float*)d_in[20], (const float*)d_in[23]};
  const float* bb[6] = {(const float*)d_in[9],  (const float*)d_in[12], (const float*)d_in[15],
                        (const float*)d_in[18], (const float*)d_in[21], (const float*)d_in[24]};
  const float* cw    = (const float*)d_in[25];
  const float* cb    = (const float*)d_in[26];
  float* out = (float*)d_out;

  // ---- workspace carve ----
  char* wsp = (char*)d_ws;
  auto alloc = [&](size_t bytes) { char* p = wsp; wsp += (bytes + 255) & ~(size_t)255; return p; };
  _Float16* B0 = (_Float16*)alloc(NBUF * 2);
  _Float16* B1 = (_Float16*)alloc(NBUF * 2);
  _Float16* B2 = (_Float16*)alloc(NBUF * 2);
  _Float16* B3 = (_Float16*)alloc(NBUF * 2);
  _Float16* wp_c1 = (_Float16*)alloc((size_t)128 * 128 * 9 * 2);
  _Float16* wp_c2 = (_Float16*)alloc((size_t)128 * 128 * 9 * 2);
  const int sci[6] = {128, 32, 64, 128, 128, 64};
  const int sco[6] = {32, 64, 128, 128, 64, 32};
  _Float16* wp_d[6];
  for (int i = 0; i < 6; ++i) wp_d[i] = (_Float16*)alloc((size_t)sco[i] * sci[i] * 49 * 2);
  float* SUMS = (float*)alloc(8704 * 4);     // 8 layer slots x 1024 + md 512
  float* s_c1 = SUMS;
  float* s_c2 = SUMS + 1024;
  float* s_l[6];
  for (int i = 0; i < 6; ++i) s_l[i] = SUMS + 2048 + i * 1024;
  float* md   = SUMS + 8192;
  float* gate = (float*)alloc(512 * 4);
  float* wd   = (float*)alloc((size_t)HW2 * 4);
  float* sa   = (float*)alloc((size_t)4 * HW2 * 4);

  // ---- batched weight pack (ws re-poisoned each call -> redo) ----
  {
    WPackArgs p;
    p.src[0] = c1w; p.dst[0] = wp_c1; p.cout[0] = 128; p.cin[0] = 128; p.kk[0] = 3;
    p.src[1] = c2w; p.dst[1] = wp_c2; p.cout[1] = 128; p.cin[1] = 128; p.kk[1] = 3;
    for (int i = 0; i < 6; ++i) {
      p.src[2 + i] = dw[i]; p.dst[2 + i] = wp_d[i];
      p.cout[2 + i] = sco[i]; p.cin[2 + i] = sci[i]; p.kk[2 + i] = 7;
    }
    p.off[0] = 0;
    for (int i = 0; i < 8; ++i) p.off[i + 1] = p.off[i] + p.cout[i] * p.cin[i] * p.kk[i] * p.kk[i];
    wpack_all<<<(p.off[8] + 255) / 256, 256, 0, stream>>>(p);
  }

  to_nhwc<<<dim3(16384 / 64, 4, 4), 256, 0, stream>>>(x, B0, 128, 16384);
  zerok<<<34, 256, 0, stream>>>(SUMS, 8704);

  const float i1 = 1.f / (float)HW1, i2 = 1.f / (float)HW2, ib = 1.f / (4.f * HW2);

  // conv1: reflect 3x3, no input norm (bias cancels under IN); stats per-(b,c)
  conv_mfma<128, 128, 3, 128, 130, true, 0, false, true><<<dim3(9 * 17, 1, 4), 256, 0, stream>>>(
      B0, wp_c1, nullptr, nullptr, nullptr, 0.f, s_c1, B1);
  // conv2: stages IN(conv1)+relu inline; stats per-(b,c)
  conv_mfma<128, 128, 3, 130, 132, true, 1, true, true><<<dim3(9 * 17, 1, 4), 256, 0, stream>>>(
      B1, wp_c2, s_c1, nullptr, nullptr, i1, s_c2, B2);

  // SFOM (idct(g*dct(x)) == g*x algebraically; mean_k dct = analytic weights)
  wdctk<<<(HW2 + 255) / 256, 256, 0, stream>>>(wd, HW2);
  mdctk<<<dim3(128, 1, 4), 256, 0, stream>>>(B2, wd, s_c2, i2, md, HW2);
  gatek<<<1, 512, 0, stream>>>(md, sa_w1, sa_w2, gate);
  { size_t tot = (size_t)4 * HW2 * 16;
    sfomk<<<(int)((tot + 255) / 256), 256, 0, stream>>>(B2, s_c2, i2, gate, B3, HW2); }

  // SPEM pyramid: 7x7 convs, each staging applies previous BN+relu inline
  conv_mfma<128, 32, 7, 132, 132, false, 0, false, false><<<dim3(9 * 9, 1, 4), 256, 0, stream>>>(
      B3, wp_d[0], nullptr, nullptr, nullptr, 0.f, s_l[0], B0);
  conv_mfma<32, 64, 7, 132, 132, false, 2, true, false><<<dim3(9 * 17, 1, 4), 256, 0, stream>>>(
      B0, wp_d[1], s_l[0], bg[0], bb[0], ib, s_l[1], B1);
  conv_mfma<64, 128, 7, 132, 132, false, 2, true, false><<<dim3(9 * 17, 1, 4), 256, 0, stream>>>(
      B1, wp_d[2], s_l[1], bg[1], bb[1], ib, s_l[2], B0);
  conv_mfma<128, 128, 7, 132, 132, false, 2, true, false><<<dim3(9 * 17, 1, 4), 256, 0, stream>>>(
      B0, wp_d[3], s_l[2], bg[2], bb[2], ib, s_l[3], B1);
  conv_mfma<128, 64, 7, 132, 132, false, 2, true, false><<<dim3(9 * 17, 1, 4), 256, 0, stream>>>(
      B1, wp_d[4], s_l[3], bg[3], bb[3], ib, s_l[4], B0);
  conv_mfma<64, 32, 7, 132, 132, false, 2, true, false><<<dim3(9 * 9, 1, 4), 256, 0, stream>>>(
      B0, wp_d[5], s_l[4], bg[4], bb[4], ib, s_l[5], B1);

  // spatial attention (L6 BN+relu inline) + final product (NCHW f32 out)
  sak<<<(4 * HW2 + 255) / 256, 256, 0, stream>>>(B1, s_l[5], ib, bg[5], bb[5], cw, cb, sa);
  finalt<<<dim3((HW2 + 63) / 64, 4, 4), 256, 0, stream>>>(B3, sa, out);
}